// Round 6
// baseline (243.486 us; speedup 1.0000x reference)
//
#include <hip/hip_runtime.h>
#include <float.h>
#include <limits.h>

#define NB     16
#define QLEN   32
#define HDIM   128
#define NPIDS  500
#define NDOCS  10000
#define DLEN   200
#define TOPK   100
#define VROW   (DLEN * HDIM)
#define NJOBS  (NB * NPIDS)
#define NBINS  (NDOCS + 1)          // key NDOCS = invalid (-1) jobs
#define NBLK   (NJOBS / 8)          // score blocks: 8 jobs per block

typedef __bf16 bf16x8 __attribute__((ext_vector_type(8)));
typedef float  f32x16 __attribute__((ext_vector_type(16)));

// ---------------- Kernel 1: per-row sort + dedupe (dup -> -1) ----------------
__global__ __launch_bounds__(512) void dedupe_kernel(const int* __restrict__ pids,
                                                     const int* __restrict__ boundaries,
                                                     int* __restrict__ dpids) {
    __shared__ int s[512];
    const int b = blockIdx.x;
    const int t = threadIdx.x;
    const int lo = boundaries[0];

    int v = INT_MAX;
    if (t < NPIDS) {
        int p = pids[b * NPIDS + t] - lo;
        if (p < 0 || p >= NDOCS) p = -1;
        v = p;
    }
    s[t] = v;
    __syncthreads();

    for (int k = 2; k <= 512; k <<= 1) {
        for (int j = k >> 1; j > 0; j >>= 1) {
            int ixj = t ^ j;
            if (ixj > t) {
                int a = s[t], c = s[ixj];
                bool up = ((t & k) == 0);
                if ((a > c) == up) { s[t] = c; s[ixj] = a; }
            }
            __syncthreads();
        }
    }

    if (t < NPIDS) {
        int val = s[t];
        int o = val;
        if (val == INT_MAX) o = -1;
        else if (t > 0 && val == s[t - 1]) o = -1;
        dpids[b * NPIDS + t] = o;
    }
}

// ---------------- job sort by pid: zero / hist / scan / scatter ----------------
__global__ __launch_bounds__(512) void zero_kernel(int* __restrict__ counts) {
    int i = blockIdx.x * 512 + threadIdx.x;
    if (i < NBINS) counts[i] = 0;
}

__global__ __launch_bounds__(512) void hist_kernel(const int* __restrict__ dpids,
                                                   int* __restrict__ counts) {
    int i = blockIdx.x * 512 + threadIdx.x;
    if (i < NJOBS) {
        int p = dpids[i];
        int key = (p < 0) ? NDOCS : p;
        atomicAdd(&counts[key], 1);
    }
}

// single-block exclusive scan over NBINS bins
__global__ __launch_bounds__(512) void scan_kernel(const int* __restrict__ counts,
                                                   int* __restrict__ offsets) {
    __shared__ int tmp[512];
    __shared__ int carry;
    const int t = threadIdx.x;
    if (t == 0) carry = 0;
    __syncthreads();

    for (int base = 0; base < NBINS; base += 512) {
        int x = (base + t < NBINS) ? counts[base + t] : 0;
        tmp[t] = x;
        __syncthreads();
        for (int off = 1; off < 512; off <<= 1) {
            int v = (t >= off) ? tmp[t - off] : 0;
            __syncthreads();
            tmp[t] += v;
            __syncthreads();
        }
        if (base + t < NBINS) offsets[base + t] = carry + tmp[t] - x;
        int btot = tmp[511];
        __syncthreads();
        if (t == 0) carry += btot;
        __syncthreads();
    }
}

__global__ __launch_bounds__(512) void scatter_kernel(const int* __restrict__ dpids,
                                                      int* __restrict__ offsets,
                                                      int* __restrict__ jobs) {
    int i = blockIdx.x * 512 + threadIdx.x;
    if (i < NJOBS) {
        int p = dpids[i];
        int key = (p < 0) ? NDOCS : p;
        int pos = atomicAdd(&offsets[key], 1);
        jobs[pos] = (key << 13) | i;        // key:14b | jobidx:13b
    }
}

// 3-way bf16 split (round-to-nearest) — the R4-verified path (absmax 0.0).
// r1 = a - (float)h and r2 = r1 - (float)m are exact (Sterbenz).
__device__ __forceinline__ void split3(float a, __bf16& h, __bf16& m, __bf16& l) {
    h = (__bf16)a;
    float r1 = a - (float)h;
    m = (__bf16)r1;
    float r2 = r1 - (float)m;
    l = (__bf16)r2;
}

__device__ __forceinline__ void split3_pack8(const float4 c0, const float4 c1,
                                             bf16x8& H, bf16x8& M, bf16x8& L) {
    float f[8] = {c0.x, c0.y, c0.z, c0.w, c1.x, c1.y, c1.z, c1.w};
    bf16x8 Ht, Mt, Lt;
    #pragma unroll
    for (int j = 0; j < 8; ++j) {
        __bf16 hh, mm, ll;
        split3(f[j], hh, mm, ll);
        Ht[j] = hh; Mt[j] = mm; Lt[j] = ll;
    }
    H = Ht; M = Mt; L = Lt;
}

// ---------------- Kernel 2: MaxSim via split-bf16 MFMA, pid-sorted jobs ----------------
// One wave per 2 consecutive jobs from the pid-sorted list (duplicate pids are
// adjacent -> same CU/XCD -> L1/L2 reuse). Numerics identical to the R4 kernel
// (RN split3 limbs, 5 MFMAs per K-step: hh, hm, mh, hl, lh).
__global__ __launch_bounds__(256) void score_kernel(const float* __restrict__ qv,
                                                    const float* __restrict__ vectors,
                                                    const int* __restrict__ jobs,
                                                    float* __restrict__ scores) {
    const int t    = threadIdx.x;
    const int w    = t >> 6;
    const int lane = t & 63;
    const int row  = lane & 31;     // q-row for A, token-in-tile for B
    const int half = lane >> 5;     // k-half selector

    // XCD swizzle: 8 XCDs x 125 contiguous blocks (1000 % 8 == 0 -> bijective)
    const int bid  = blockIdx.x;
    const int gblk = (bid & 7) * (NBLK / 8) + (bid >> 3);
    const int j0   = (gblk * 4 + w) * 2;

    for (int jj = j0; jj < j0 + 2; ++jj) {
        const int e      = jobs[jj];
        const int key    = e >> 13;
        const int jobidx = e & 8191;
        if (key >= NDOCS) {
            if (lane == 0) scores[jobidx] = -__builtin_inff();
            continue;
        }
        const int b = jobidx / NPIDS;

        // ---- load + split Q fragments for this job's batch ----
        bf16x8 qh[8], qm[8], ql[8];
        {
            const float* qb = qv + ((size_t)b * QLEN + row) * HDIM + half * 8;
            #pragma unroll
            for (int ks = 0; ks < 8; ++ks) {
                const float4 a0 = *(const float4*)(qb + ks * 16);
                const float4 a1 = *(const float4*)(qb + ks * 16 + 4);
                split3_pack8(a0, a1, qh[ks], qm[ks], ql[ks]);
            }
        }

        const float* vb = vectors + (size_t)key * VROW + half * 8;

        float rmax[16];
        #pragma unroll
        for (int j = 0; j < 16; ++j) rmax[j] = -FLT_MAX;

        for (int tile = 0; tile < 7; ++tile) {
            int tok = tile * 32 + row;
            if (tok > DLEN - 1) tok = DLEN - 1;          // dup token 199: max-safe
            const float* vt = vb + (size_t)tok * HDIM;

            f32x16 acc;
            #pragma unroll
            for (int j = 0; j < 16; ++j) acc[j] = 0.0f;

            #pragma unroll
            for (int ks = 0; ks < 8; ++ks) {
                const float4 c0 = *(const float4*)(vt + ks * 16);
                const float4 c1 = *(const float4*)(vt + ks * 16 + 4);
                bf16x8 vh, vm, vl;
                split3_pack8(c0, c1, vh, vm, vl);
                acc = __builtin_amdgcn_mfma_f32_32x32x16_bf16(qh[ks], vh, acc, 0, 0, 0);
                acc = __builtin_amdgcn_mfma_f32_32x32x16_bf16(qh[ks], vm, acc, 0, 0, 0);
                acc = __builtin_amdgcn_mfma_f32_32x32x16_bf16(qm[ks], vh, acc, 0, 0, 0);
                acc = __builtin_amdgcn_mfma_f32_32x32x16_bf16(qh[ks], vl, acc, 0, 0, 0);
                acc = __builtin_amdgcn_mfma_f32_32x32x16_bf16(ql[ks], vh, acc, 0, 0, 0);
            }

            #pragma unroll
            for (int j = 0; j < 16; ++j) rmax[j] = fmaxf(rmax[j], acc[j]);
        }

        double dsum = 0.0;
        #pragma unroll
        for (int j = 0; j < 16; ++j) {
            float m = rmax[j];
            m = fmaxf(m, __shfl_xor(m, 1));
            m = fmaxf(m, __shfl_xor(m, 2));
            m = fmaxf(m, __shfl_xor(m, 4));
            m = fmaxf(m, __shfl_xor(m, 8));
            m = fmaxf(m, __shfl_xor(m, 16));
            dsum += (double)m;
        }
        dsum += __shfl_xor(dsum, 32);
        if (lane == 0) scores[jobidx] = (float)dsum;
    }
}

// ---------------- Kernel 3: per-batch top-100 (sorted desc) ----------------
__global__ __launch_bounds__(512) void topk_kernel(const float* __restrict__ scores,
                                                   const int* __restrict__ dpids,
                                                   const int* __restrict__ boundaries,
                                                   float* __restrict__ out) {
    __shared__ float ss[512];
    __shared__ int   sp[512];
    const int b = blockIdx.x;
    const int t = threadIdx.x;
    const int lo = boundaries[0];

    float sc = -__builtin_inff();
    int   p  = -1;
    if (t < NPIDS) {
        p = dpids[b * NPIDS + t];
        sc = (p < 0) ? -__builtin_inff() : scores[b * NPIDS + t];
    }
    ss[t] = sc;
    sp[t] = p;
    __syncthreads();

    for (int k = 2; k <= 512; k <<= 1) {
        for (int j = k >> 1; j > 0; j >>= 1) {
            int ixj = t ^ j;
            if (ixj > t) {
                float a = ss[t], c = ss[ixj];
                bool down = ((t & k) == 0);
                bool swap = down ? (a < c) : (a > c);
                if (swap) {
                    int pa = sp[t], pc = sp[ixj];
                    ss[t] = c;   ss[ixj] = a;
                    sp[t] = pc;  sp[ixj] = pa;
                }
            }
            __syncthreads();
        }
    }

    if (t < TOPK) {
        out[b * TOPK + t] = ss[t];
        int pp = sp[t];
        out[NB * TOPK + b * TOPK + t] = (pp >= 0) ? (float)(pp + lo) : -1.0f;
    }
}

// ---------------- launch ----------------
extern "C" void kernel_launch(void* const* d_in, const int* in_sizes, int n_in,
                              void* d_out, int out_size, void* d_ws, size_t ws_size,
                              hipStream_t stream) {
    const float* qv        = (const float*)d_in[0];
    const int*   pids      = (const int*)d_in[1];
    const float* vectors   = (const float*)d_in[2];
    const int*   boundaries= (const int*)d_in[3];

    char* ws = (char*)d_ws;
    int*   dpids   = (int*)(ws);                     // 8000 int
    float* scores  = (float*)(ws + 32768);           // 8000 float
    int*   counts  = (int*)(ws + 65536);             // 10001 int
    int*   offsets = (int*)(ws + 110592);            // 10001 int
    int*   jobs    = (int*)(ws + 155648);            // 8000 int

    dedupe_kernel <<<NB, 512, 0, stream>>>(pids, boundaries, dpids);
    zero_kernel   <<<(NBINS + 511) / 512, 512, 0, stream>>>(counts);
    hist_kernel   <<<(NJOBS + 511) / 512, 512, 0, stream>>>(dpids, counts);
    scan_kernel   <<<1, 512, 0, stream>>>(counts, offsets);
    scatter_kernel<<<(NJOBS + 511) / 512, 512, 0, stream>>>(dpids, offsets, jobs);
    score_kernel  <<<NBLK, 256, 0, stream>>>(qv, vectors, jobs, scores);
    topk_kernel   <<<NB, 512, 0, stream>>>(scores, dpids, boundaries, (float*)d_out);
}

// Round 7
// 164.149 us; speedup vs baseline: 1.4833x; 1.4833x over previous
//
#include <hip/hip_runtime.h>
#include <float.h>
#include <limits.h>

#define NB     16
#define QLEN   32
#define HDIM   128
#define NPIDS  500
#define NDOCS  10000
#define DLEN   200
#define TOPK   100
#define VROW   (DLEN * HDIM)

typedef __bf16 bf16x8 __attribute__((ext_vector_type(8)));
typedef float  f32x16 __attribute__((ext_vector_type(16)));

// ---------------- Kernel 1: per-row sort + dedupe (dup -> -1) ----------------
__global__ __launch_bounds__(512) void dedupe_kernel(const int* __restrict__ pids,
                                                     const int* __restrict__ boundaries,
                                                     int* __restrict__ dpids) {
    __shared__ int s[512];
    const int b = blockIdx.x;
    const int t = threadIdx.x;
    const int lo = boundaries[0];

    int v = INT_MAX;
    if (t < NPIDS) {
        int p = pids[b * NPIDS + t] - lo;
        if (p < 0 || p >= NDOCS) p = -1;
        v = p;
    }
    s[t] = v;
    __syncthreads();

    for (int k = 2; k <= 512; k <<= 1) {
        for (int j = k >> 1; j > 0; j >>= 1) {
            int ixj = t ^ j;
            if (ixj > t) {
                int a = s[t], c = s[ixj];
                bool up = ((t & k) == 0);
                if ((a > c) == up) { s[t] = c; s[ixj] = a; }
            }
            __syncthreads();
        }
    }

    if (t < NPIDS) {
        int val = s[t];
        int o = val;
        if (val == INT_MAX) o = -1;
        else if (t > 0 && val == s[t - 1]) o = -1;
        dpids[b * NPIDS + t] = o;
    }
}

// 3-way bf16 split (round-to-nearest) — the R4-verified path (absmax 0.0).
// r1 = a - (float)h and r2 = r1 - (float)m are exact (Sterbenz).
__device__ __forceinline__ void split3(float a, __bf16& h, __bf16& m, __bf16& l) {
    h = (__bf16)a;
    float r1 = a - (float)h;
    m = (__bf16)r1;
    float r2 = r1 - (float)m;
    l = (__bf16)r2;
}

__device__ __forceinline__ void split3_pack8(const float4 c0, const float4 c1,
                                             bf16x8& H, bf16x8& M, bf16x8& L) {
    float f[8] = {c0.x, c0.y, c0.z, c0.w, c1.x, c1.y, c1.z, c1.w};
    bf16x8 Ht, Mt, Lt;
    #pragma unroll
    for (int j = 0; j < 8; ++j) {
        __bf16 hh, mm, ll;
        split3(f[j], hh, mm, ll);
        Ht[j] = hh; Mt[j] = mm; Lt[j] = ll;
    }
    H = Ht; M = Mt; L = Lt;
}

// ---------------- Kernel 2: MaxSim via split-bf16 MFMA + depth-4 prefetch ----------------
// One wave per 2 consecutive candidates (same batch: 500 even, pairs aligned).
// Numerics bit-identical to the R4 kernel (RN split3 limbs, MFMA order
// hh,hm,mh,hl,lh). New: depth-4 circular register prefetch over the 56 flat
// V-chunks (chunk = tile*8+ks, 32B/lane each) so 4 chunk-pairs (8 loads,
// 2KB/lane-wave... 4x2KB per wave) stay in flight across the split+MFMA
// compute — covers ~900cyc HBM latency at 2 waves/SIMD.
__global__ __launch_bounds__(256, 2) void score_kernel(const float* __restrict__ qv,
                                                       const float* __restrict__ vectors,
                                                       const int* __restrict__ dpids,
                                                       float* __restrict__ scores) {
    const int t    = threadIdx.x;
    const int w    = t >> 6;
    const int lane = t & 63;
    const int row  = lane & 31;     // q-row for A, token-in-tile for B
    const int half = lane >> 5;     // k-half selector

    const int cbase = (blockIdx.x * 4 + w) * 2;
    const int b     = cbase / NPIDS;

    // ---- load + split Q fragments (stationary for both candidates) ----
    bf16x8 qh[8], qm[8], ql[8];
    {
        const float* qb = qv + ((size_t)b * QLEN + row) * HDIM + half * 8;
        #pragma unroll
        for (int ks = 0; ks < 8; ++ks) {
            const float4 a0 = *(const float4*)(qb + ks * 16);
            const float4 a1 = *(const float4*)(qb + ks * 16 + 4);
            split3_pack8(a0, a1, qh[ks], qm[ks], ql[ks]);
        }
    }

    for (int ci = 0; ci < 2; ++ci) {
        const int c   = cbase + ci;
        const int pid = dpids[c];
        if (pid < 0) {
            if (lane == 0) scores[c] = -__builtin_inff();
            continue;
        }

        const float* vb = vectors + (size_t)pid * VROW + half * 8;

        float rmax[16];
        #pragma unroll
        for (int j = 0; j < 16; ++j) rmax[j] = -FLT_MAX;

        // ---- prologue: prefetch chunks 0..3 (tile 0, ks 0..3) ----
        const float* vt0 = vb + (size_t)row * HDIM;   // tile 0: tok = row < 200
        float4 pf[4][2];
        #pragma unroll
        for (int s = 0; s < 4; ++s) {
            pf[s][0] = *(const float4*)(vt0 + s * 16);
            pf[s][1] = *(const float4*)(vt0 + s * 16 + 4);
        }

        #pragma unroll 1
        for (int tile = 0; tile < 7; ++tile) {
            int tok = tile * 32 + row;
            if (tok > DLEN - 1) tok = DLEN - 1;            // dup token 199: max-safe
            const float* vt = vb + (size_t)tok * HDIM;
            int tokn = (tile + 1) * 32 + row;
            if (tokn > DLEN - 1) tokn = DLEN - 1;
            const float* vtn = vb + (size_t)tokn * HDIM;   // next tile base

            f32x16 acc;
            #pragma unroll
            for (int j = 0; j < 16; ++j) acc[j] = 0.0f;

            #pragma unroll
            for (int ks = 0; ks < 8; ++ks) {
                const int slot = ks & 3;                   // compile-time in unroll
                const float4 c0 = pf[slot][0];
                const float4 c1 = pf[slot][1];

                // issue chunk +4 into the freed slot
                if (ks < 4) {
                    pf[slot][0] = *(const float4*)(vt + (ks + 4) * 16);
                    pf[slot][1] = *(const float4*)(vt + (ks + 4) * 16 + 4);
                } else if (tile < 6) {
                    pf[slot][0] = *(const float4*)(vtn + (ks - 4) * 16);
                    pf[slot][1] = *(const float4*)(vtn + (ks - 4) * 16 + 4);
                }

                bf16x8 vh, vm, vl;
                split3_pack8(c0, c1, vh, vm, vl);
                acc = __builtin_amdgcn_mfma_f32_32x32x16_bf16(qh[ks], vh, acc, 0, 0, 0);
                acc = __builtin_amdgcn_mfma_f32_32x32x16_bf16(qh[ks], vm, acc, 0, 0, 0);
                acc = __builtin_amdgcn_mfma_f32_32x32x16_bf16(qm[ks], vh, acc, 0, 0, 0);
                acc = __builtin_amdgcn_mfma_f32_32x32x16_bf16(qh[ks], vl, acc, 0, 0, 0);
                acc = __builtin_amdgcn_mfma_f32_32x32x16_bf16(ql[ks], vh, acc, 0, 0, 0);
            }

            #pragma unroll
            for (int j = 0; j < 16; ++j) rmax[j] = fmaxf(rmax[j], acc[j]);
        }

        // cross-lane max over the 32 token-columns per q-row, then double-sum.
        double dsum = 0.0;
        #pragma unroll
        for (int j = 0; j < 16; ++j) {
            float m = rmax[j];
            m = fmaxf(m, __shfl_xor(m, 1));
            m = fmaxf(m, __shfl_xor(m, 2));
            m = fmaxf(m, __shfl_xor(m, 4));
            m = fmaxf(m, __shfl_xor(m, 8));
            m = fmaxf(m, __shfl_xor(m, 16));
            dsum += (double)m;
        }
        dsum += __shfl_xor(dsum, 32);
        if (lane == 0) scores[c] = (float)dsum;
    }
}

// ---------------- Kernel 3: per-batch top-100 (sorted desc) ----------------
__global__ __launch_bounds__(512) void topk_kernel(const float* __restrict__ scores,
                                                   const int* __restrict__ dpids,
                                                   const int* __restrict__ boundaries,
                                                   float* __restrict__ out) {
    __shared__ float ss[512];
    __shared__ int   sp[512];
    const int b = blockIdx.x;
    const int t = threadIdx.x;
    const int lo = boundaries[0];

    float sc = -__builtin_inff();
    int   p  = -1;
    if (t < NPIDS) {
        p = dpids[b * NPIDS + t];
        sc = (p < 0) ? -__builtin_inff() : scores[b * NPIDS + t];
    }
    ss[t] = sc;
    sp[t] = p;
    __syncthreads();

    for (int k = 2; k <= 512; k <<= 1) {
        for (int j = k >> 1; j > 0; j >>= 1) {
            int ixj = t ^ j;
            if (ixj > t) {
                float a = ss[t], c = ss[ixj];
                bool down = ((t & k) == 0);
                bool swap = down ? (a < c) : (a > c);
                if (swap) {
                    int pa = sp[t], pc = sp[ixj];
                    ss[t] = c;   ss[ixj] = a;
                    sp[t] = pc;  sp[ixj] = pa;
                }
            }
            __syncthreads();
        }
    }

    if (t < TOPK) {
        out[b * TOPK + t] = ss[t];
        int pp = sp[t];
        out[NB * TOPK + b * TOPK + t] = (pp >= 0) ? (float)(pp + lo) : -1.0f;
    }
}

// ---------------- launch ----------------
extern "C" void kernel_launch(void* const* d_in, const int* in_sizes, int n_in,
                              void* d_out, int out_size, void* d_ws, size_t ws_size,
                              hipStream_t stream) {
    const float* qv        = (const float*)d_in[0];
    const int*   pids      = (const int*)d_in[1];
    const float* vectors   = (const float*)d_in[2];
    const int*   boundaries= (const int*)d_in[3];

    int*   dpids  = (int*)d_ws;
    float* scores = (float*)((char*)d_ws + 32768);

    dedupe_kernel<<<NB, 512, 0, stream>>>(pids, boundaries, dpids);
    score_kernel <<<(NB * NPIDS) / 8, 256, 0, stream>>>(qv, vectors, dpids, scores);
    topk_kernel  <<<NB, 512, 0, stream>>>(scores, dpids, boundaries, (float*)d_out);
}